// Round 1
// baseline (129.370 us; speedup 1.0000x reference)
//
#include <hip/hip_runtime.h>

#define NEXP 5
#define MAXF 128
#define NOUT 512
#define TPB  64
#define PITCH 136   // ushorts per LDS x-row: 128 + 8 pad (272 B stride = 68 dwords -> 8 bank residues)

typedef __attribute__((ext_vector_type(8))) short short8;
typedef __attribute__((ext_vector_type(4))) float floatx4;

__device__ __forceinline__ ushort f2bf(float f) {   // RNE fp32->bf16
    uint u = __float_as_uint(f);
    u += 0x7FFF + ((u >> 16) & 1);
    return (ushort)(u >> 16);
}

// One expert's tokens for this block: B-frags + bias hoisted once per wave,
// then <=4 sub-groups of 16 tokens through mfma_f32_16x16x32_bf16.
// Frag layouts identical to the previously verified kernel:
//   A lane l: row = perm-token(m=l&15), k = s*32 + (l>>4)*8 + j
//   B lane l: col = nbase + bi*16 + (l&15), k = s*32 + (l>>4)*8 + j  (zero for k>=K)
//   C lane l: row = (l>>4)*4 + r, col = nbase + bi*16 + (l&15)
template <int E>
__device__ __forceinline__ void run_expert(
    const ushort* __restrict__ xs, const int* __restrict__ perm,
    const float* __restrict__ w, const float* __restrict__ b,
    float* __restrict__ out, int t0, int boff, int c, int lane, int nbase) {
    constexpr int NS = (E == 4) ? 4 : (E == 3) ? 2 : 1;
    constexpr int K = 8 << E;
    const int m = lane & 15, q = lane >> 4;

    short8 bf[NS][4];
    #pragma unroll
    for (int s = 0; s < NS; ++s) {
        const int k0 = s * 32 + q * 8;
        #pragma unroll
        for (int bi = 0; bi < 4; ++bi) {
            const float* wr = w + ((size_t)E * NOUT + (nbase + bi * 16 + m)) * MAXF + k0;
            short8 v;
            #pragma unroll
            for (int j = 0; j < 8; ++j)
                v[j] = (short)((k0 + j < K) ? f2bf(wr[j]) : (ushort)0);
            bf[s][bi] = v;
        }
    }
    float bv[4];
    #pragma unroll
    for (int bi = 0; bi < 4; ++bi) bv[bi] = b[E * NOUT + nbase + bi * 16 + m];

    for (int o = 0; o < c; o += 16) {
        const int L = (c - o > 16) ? 16 : (c - o);
        const int idx = (m < L) ? m : (L - 1);
        const int row = perm[boff + o + idx];
        const ushort* xr = xs + row * PITCH + q * 8;
        floatx4 acc[4];
        #pragma unroll
        for (int bi = 0; bi < 4; ++bi)
            acc[bi] = floatx4{bv[bi], bv[bi], bv[bi], bv[bi]};
        #pragma unroll
        for (int s = 0; s < NS; ++s) {
            const short8 af = *(const short8*)(xr + s * 32);
            #pragma unroll
            for (int bi = 0; bi < 4; ++bi)
                acc[bi] = __builtin_amdgcn_mfma_f32_16x16x32_bf16(af, bf[s][bi], acc[bi], 0, 0, 0);
        }
        #pragma unroll
        for (int r = 0; r < 4; ++r) {
            const int mi = q * 4 + r;
            if (mi < L) {
                const int trow = perm[boff + o + mi];   // LDS broadcast per 16-lane group
                float* orow = out + ((size_t)(t0 + trow)) * NOUT + nbase + m;
                #pragma unroll
                for (int bi = 0; bi < 4; ++bi) orow[bi * 16] = acc[bi][r];
            }
        }
    }
}

// Single fused kernel: 64 consecutive tokens per block; block-local counting sort
// by expert in LDS; x staged fp32->bf16 into LDS; w/bias read fp32 + converted
// in-register; out written directly. No workspace, no prep dispatch, no memset.
__global__ __launch_bounds__(512) void misl_fused(
    const float* __restrict__ x, const int* __restrict__ feat,
    const float* __restrict__ w, const float* __restrict__ b,
    float* __restrict__ out, int n) {
    __shared__ ushort xs[TPB * PITCH];
    __shared__ int perm[TPB];
    __shared__ int cnt[NEXP];
    __shared__ int base[NEXP];

    const int tid = threadIdx.x;
    const int t0 = blockIdx.x * TPB;
    const int nt = (n - t0 < TPB) ? (n - t0) : TPB;

    if (tid < NEXP) cnt[tid] = 0;

    // stage x: each thread owns 16 consecutive floats of the block's 64x128 slab
    const int row = tid >> 3;
    const int col = (tid & 7) * 16;
    float4 a0, a1, a2, a3;
    const bool stage = (row < nt);
    if (stage) {
        const float* xp = x + (size_t)t0 * MAXF + tid * 16;
        a0 = *(const float4*)xp;
        a1 = *(const float4*)(xp + 4);
        a2 = *(const float4*)(xp + 8);
        a3 = *(const float4*)(xp + 12);
    }
    __syncthreads();                               // cnt zeroed

    int e = 0, r = 0;
    if (tid < nt) {
        e = __ffs((uint)feat[t0 + tid]) - 4;       // 8->0,16->1,32->2,64->3,128->4
        r = atomicAdd(&cnt[e], 1);
    }
    if (stage) {
        short8 v0, v1;
        v0[0] = (short)f2bf(a0.x); v0[1] = (short)f2bf(a0.y);
        v0[2] = (short)f2bf(a0.z); v0[3] = (short)f2bf(a0.w);
        v0[4] = (short)f2bf(a1.x); v0[5] = (short)f2bf(a1.y);
        v0[6] = (short)f2bf(a1.z); v0[7] = (short)f2bf(a1.w);
        v1[0] = (short)f2bf(a2.x); v1[1] = (short)f2bf(a2.y);
        v1[2] = (short)f2bf(a2.z); v1[3] = (short)f2bf(a2.w);
        v1[4] = (short)f2bf(a3.x); v1[5] = (short)f2bf(a3.y);
        v1[6] = (short)f2bf(a3.z); v1[7] = (short)f2bf(a3.w);
        *(short8*)(xs + row * PITCH + col)     = v0;
        *(short8*)(xs + row * PITCH + col + 8) = v1;
    }
    __syncthreads();                               // cnt final
    if (tid == 0) {                                // heavy experts first in perm
        int o = 0;
        #pragma unroll
        for (int j = NEXP - 1; j >= 0; --j) { base[j] = o; o += cnt[j]; }
    }
    __syncthreads();                               // base ready
    if (tid < nt) perm[base[e] + r] = tid;
    __syncthreads();                               // perm + xs ready

    const int lane = tid & 63;
    const int nbase = (tid >> 6) << 6;             // wave -> 64-col slice
    const int c0 = cnt[0], c1 = cnt[1], c2 = cnt[2], c3 = cnt[3], c4 = cnt[4];
    const int b0 = base[0], b1 = base[1], b2 = base[2], b3 = base[3], b4 = base[4];

    if (c4) run_expert<4>(xs, perm, w, b, out, t0, b4, c4, lane, nbase);
    if (c3) run_expert<3>(xs, perm, w, b, out, t0, b3, c3, lane, nbase);
    if (c2) run_expert<2>(xs, perm, w, b, out, t0, b2, c2, lane, nbase);
    if (c1) run_expert<1>(xs, perm, w, b, out, t0, b1, c1, lane, nbase);
    if (c0) run_expert<0>(xs, perm, w, b, out, t0, b0, c0, lane, nbase);
}

extern "C" void kernel_launch(void* const* d_in, const int* in_sizes, int n_in,
                              void* d_out, int out_size, void* d_ws, size_t ws_size,
                              hipStream_t stream) {
    const float* x    = (const float*)d_in[0];
    const int*   feat = (const int*)d_in[1];
    const float* w    = (const float*)d_in[2];
    const float* b    = (const float*)d_in[3];
    float* out = (float*)d_out;

    const int n = in_sizes[1];                     // tokens = 32768
    const int nblk = (n + TPB - 1) / TPB;          // 512 blocks x 512 threads
    misl_fused<<<nblk, 512, 0, stream>>>(x, feat, w, b, out, n);
}

// Round 2
// 98.115 us; speedup vs baseline: 1.3186x; 1.3186x over previous
//
#include <hip/hip_runtime.h>

#define NEXP 5
#define MAXF 128
#define NOUT 512
#define PERMOFF 64
#define TPB 64
#define PITCH 136   // ushorts per LDS x-row (272 B stride)

typedef __attribute__((ext_vector_type(8))) short short8;
typedef __attribute__((ext_vector_type(4))) float floatx4;

__device__ __forceinline__ ushort f2bf(float f) {   // RNE fp32->bf16
    uint u = __float_as_uint(f);
    u += 0x7FFF + ((u >> 16) & 1);
    return (ushort)(u >> 16);
}

// ws ints: [8..12] = per-expert scatter cursors (memset 0),
// [PERMOFF + e*n + i] = perm (fixed per-expert segment bases).
// Then 256B-aligned: wb bf16[5][4][32][64][8] (B-frag order, zero-padded past K).

// blocks [0,nb): token scatter; [nb,nb+160): W fp32->bf16 frag pack. No x pass.
__global__ __launch_bounds__(256) void misl_prep(
    const int* __restrict__ feat, const float* __restrict__ w,
    int* __restrict__ ws, ushort* __restrict__ wb, int n, int nb) {
    const int tid = threadIdx.x;
    if ((int)blockIdx.x < nb) {
        __shared__ int lcnt[NEXP], lbase[NEXP];
        if (tid < NEXP) lcnt[tid] = 0;
        __syncthreads();
        const int t = blockIdx.x * 256 + tid;
        int e = 0, r = 0;
        if (t < n) {
            e = __ffs((uint)feat[t]) - 4;   // 8->0,16->1,32->2,64->3,128->4
            r = atomicAdd(&lcnt[e], 1);
        }
        __syncthreads();
        if (tid < NEXP) lbase[tid] = atomicAdd(&ws[8 + tid], lcnt[tid]);
        __syncthreads();
        if (t < n) ws[PERMOFF + e * n + lbase[e] + r] = t;
    } else {
        const int idx = ((int)blockIdx.x - nb) * 256 + tid;  // 0..40959
        const int lane = idx & 63, nb16 = (idx >> 6) & 31;
        const int s = (idx >> 11) & 3, e = idx >> 13;
        if (e < NEXP) {
            const int ncol = nb16 * 16 + (lane & 15);
            const int k0 = s * 32 + (lane >> 4) * 8;
            const int K = 8 << e;
            const float* wr = w + ((size_t)e * NOUT + ncol) * MAXF + k0;
            short8 v;
            #pragma unroll
            for (int j = 0; j < 8; ++j)
                v[j] = (short)((k0 + j < K) ? f2bf(wr[j]) : (ushort)0);
            *(short8*)(wb + (size_t)idx * 8) = v;
        }
    }
}

// wave = 16 tokens x 64 cols; 8 waves/block -> 64 tokens x 512 cols per block.
// A-frags from LDS-staged bf16 x rows; B-frags + bias hoisted per wave from
// prepacked bf16 wb (16B loads, no conversion in the hot kernel).
template <int NS>
__device__ __forceinline__ void mfma_run(
    const ushort* __restrict__ xs, const int* __restrict__ tokl,
    const ushort* __restrict__ wbe, const float* __restrict__ be,
    int rem, int lane, int n_base, float* __restrict__ out) {
    const int m = lane & 15, q = lane >> 4;
    const int nb16 = n_base >> 4;
    short8 bf[NS][4];
    #pragma unroll
    for (int s = 0; s < NS; ++s)
        #pragma unroll
        for (int bi = 0; bi < 4; ++bi)
            bf[s][bi] = *(const short8*)(wbe + ((size_t)(s * 32 + nb16 + bi) * 64 + lane) * 8);
    float bv[4];
    #pragma unroll
    for (int bi = 0; bi < 4; ++bi) bv[bi] = be[n_base + bi * 16 + m];

    const int trips = (rem + 15) >> 4;          // <= 4
    for (int g = 0; g < trips; ++g) {
        const int base = g * 16;
        const int lim = rem - base;             // >= 1
        const int idx = (m < lim) ? m : lim - 1;
        const ushort* xr = xs + (size_t)(base + idx) * PITCH + q * 8;
        floatx4 acc[4];
        #pragma unroll
        for (int bi = 0; bi < 4; ++bi)
            acc[bi] = floatx4{bv[bi], bv[bi], bv[bi], bv[bi]};
        #pragma unroll
        for (int s = 0; s < NS; ++s) {
            const short8 af = *(const short8*)(xr + s * 32);
            #pragma unroll
            for (int bi = 0; bi < 4; ++bi)
                acc[bi] = __builtin_amdgcn_mfma_f32_16x16x32_bf16(af, bf[s][bi], acc[bi], 0, 0, 0);
        }
        #pragma unroll
        for (int r = 0; r < 4; ++r) {
            const int mi = q * 4 + r;
            if (mi < lim) {
                const int tr = tokl[base + mi];          // LDS broadcast
                float* orow = out + (size_t)tr * NOUT + n_base + m;
                #pragma unroll
                for (int bi = 0; bi < 4; ++bi) orow[bi * 16] = acc[bi][r];
            }
        }
    }
}

__global__ __launch_bounds__(512, 4) void misl_main(
    const float* __restrict__ x, const ushort* __restrict__ wb,
    const float* __restrict__ b, const int* __restrict__ ws,
    float* __restrict__ out, int n) {
    __shared__ ushort xs[TPB * PITCH];
    __shared__ int tokl[TPB];

    const int g = blockIdx.x;
    const int c[NEXP] = {ws[8], ws[9], ws[10], ws[11], ws[12]};

    int gb = 0, e = -1, lgs = 0;                // heavy experts first
    #pragma unroll
    for (int j = 0; j < NEXP; ++j) {
        const int ee = 4 - j;
        const int ng = (c[ee] + 63) >> 6;
        if (e < 0 && g < gb + ng) { e = ee; lgs = g - gb; }
        gb += ng;
    }
    if (e < 0) return;

    int rem = c[e] - lgs * 64;
    if (rem > 64) rem = 64;
    const int* tokp = ws + PERMOFF + e * n + lgs * 64;

    // stage this block's (permuted) 64 token rows fp32 -> bf16 into LDS
    const int tid = threadIdx.x;
    const int row = tid >> 3;                   // 0..63
    const int colu = (tid & 7) * 16;            // 0..112 ushorts
    if (row < rem) {
        const int tok = tokp[row];
        if ((tid & 7) == 0) tokl[row] = tok;
        const float* xp = x + (size_t)tok * MAXF + colu;
        const float4 a0 = *(const float4*)xp;
        const float4 a1 = *(const float4*)(xp + 4);
        const float4 a2 = *(const float4*)(xp + 8);
        const float4 a3 = *(const float4*)(xp + 12);
        short8 v0, v1;
        v0[0] = (short)f2bf(a0.x); v0[1] = (short)f2bf(a0.y);
        v0[2] = (short)f2bf(a0.z); v0[3] = (short)f2bf(a0.w);
        v0[4] = (short)f2bf(a1.x); v0[5] = (short)f2bf(a1.y);
        v0[6] = (short)f2bf(a1.z); v0[7] = (short)f2bf(a1.w);
        v1[0] = (short)f2bf(a2.x); v1[1] = (short)f2bf(a2.y);
        v1[2] = (short)f2bf(a2.z); v1[3] = (short)f2bf(a2.w);
        v1[4] = (short)f2bf(a3.x); v1[5] = (short)f2bf(a3.y);
        v1[6] = (short)f2bf(a3.z); v1[7] = (short)f2bf(a3.w);
        *(short8*)(xs + (size_t)row * PITCH + colu)     = v0;
        *(short8*)(xs + (size_t)row * PITCH + colu + 8) = v1;
    }
    __syncthreads();

    const int lane = tid & 63;
    const int n_base = (tid >> 6) * 64;         // wave -> 64-col slice
    const ushort* wbe = wb + (size_t)e * 4 * 32 * 64 * 8;
    const float* be = b + e * NOUT;

    switch (e) {
        case 0: mfma_run<1>(xs, tokl, wbe, be, rem, lane, n_base, out); break;
        case 1: mfma_run<1>(xs, tokl, wbe, be, rem, lane, n_base, out); break;
        case 2: mfma_run<1>(xs, tokl, wbe, be, rem, lane, n_base, out); break;
        case 3: mfma_run<2>(xs, tokl, wbe, be, rem, lane, n_base, out); break;
        case 4: mfma_run<4>(xs, tokl, wbe, be, rem, lane, n_base, out); break;
    }
}

extern "C" void kernel_launch(void* const* d_in, const int* in_sizes, int n_in,
                              void* d_out, int out_size, void* d_ws, size_t ws_size,
                              hipStream_t stream) {
    const float* x    = (const float*)d_in[0];
    const int*   feat = (const int*)d_in[1];
    const float* w    = (const float*)d_in[2];
    const float* b    = (const float*)d_in[3];
    float* out = (float*)d_out;
    int*   ws  = (int*)d_ws;

    const int n  = in_sizes[1];                   // tokens = 32768
    const int nb = (n + 255) / 256;               // 128

    const size_t wb_off = (((size_t)(PERMOFF + (size_t)NEXP * n) * 4) + 255) & ~(size_t)255;
    ushort* wb = (ushort*)((char*)d_ws + wb_off); // 655 KB bf16 frag pack

    hipMemsetAsync(ws, 0, 64 * sizeof(int), stream);          // zero cursors
    misl_prep<<<nb + 160, 256, 0, stream>>>(feat, w, ws, wb, n, nb);
    misl_main<<<(n + 63) / 64 + NEXP, 512, 0, stream>>>(x, wb, b, ws, out, n);
}

// Round 3
// 94.821 us; speedup vs baseline: 1.3644x; 1.0347x over previous
//
#include <hip/hip_runtime.h>

#define NEXP 5
#define MAXF 128
#define NOUT 512
#define TPB  64
#define PITCH 136   // ushorts per LDS x-row (272 B stride; rows 8 apart alias -> 2-way, free)

typedef __attribute__((ext_vector_type(8))) short short8;
typedef __attribute__((ext_vector_type(4))) float floatx4;

__device__ __forceinline__ ushort f2bf(float f) {   // RNE fp32->bf16
    uint u = __float_as_uint(f);
    u += 0x7FFF + ((u >> 16) & 1);
    return (ushort)(u >> 16);
}

// wb bf16 [5][4][32][64][8]: B-frag order, idx = ((e*4+s)*32 + nb16)*64 + lane,
// elem j at k = s*32 + (lane>>4)*8 + j, col = nb16*16 + (lane&15); zero past K.
__global__ __launch_bounds__(256) void misl_pack(
    const float* __restrict__ w, ushort* __restrict__ wb) {
    const int idx = blockIdx.x * 256 + threadIdx.x;   // 0..40959
    const int lane = idx & 63, nb16 = (idx >> 6) & 31;
    const int s = (idx >> 11) & 3, e = idx >> 13;
    if (e < NEXP) {
        const int ncol = nb16 * 16 + (lane & 15);
        const int k0 = s * 32 + (lane >> 4) * 8;
        const int K = 8 << e;
        const float* wr = w + ((size_t)e * NOUT + ncol) * MAXF + k0;
        short8 v;
        #pragma unroll
        for (int j = 0; j < 8; ++j)
            v[j] = (short)((k0 + j < K) ? f2bf(wr[j]) : (ushort)0);
        *(short8*)(wb + (size_t)idx * 8) = v;
    }
}

// One expert's tokens in this block: B-frags + bias hoisted per wave (16B vector
// loads from prepacked wb), <=4 ragged 16-token groups through 16x16x32 MFMA.
// Frag layouts identical to the round-0/2 verified kernel.
template <int E>
__device__ __forceinline__ void run_expert(
    const ushort* __restrict__ xs, const int* __restrict__ perm,
    const ushort* __restrict__ wb, const float* __restrict__ b,
    float* __restrict__ out, int t0, int boff, int c, int lane, int n_base) {
    constexpr int NS = (E == 4) ? 4 : (E == 3) ? 2 : 1;
    const int m = lane & 15, q = lane >> 4;
    const int nb16 = n_base >> 4;
    const ushort* wbe = wb + (size_t)E * 4 * 32 * 64 * 8;

    short8 bf[NS][4];
    #pragma unroll
    for (int s = 0; s < NS; ++s)
        #pragma unroll
        for (int bi = 0; bi < 4; ++bi)
            bf[s][bi] = *(const short8*)(wbe + ((size_t)(s * 32 + nb16 + bi) * 64 + lane) * 8);
    float bv[4];
    #pragma unroll
    for (int bi = 0; bi < 4; ++bi) bv[bi] = b[E * NOUT + n_base + bi * 16 + m];

    for (int o = 0; o < c; o += 16) {
        const int L = (c - o > 16) ? 16 : (c - o);
        const int idx = (m < L) ? m : (L - 1);
        const int row = perm[boff + o + idx];
        const ushort* xr = xs + (size_t)row * PITCH + q * 8;
        floatx4 acc[4];
        #pragma unroll
        for (int bi = 0; bi < 4; ++bi)
            acc[bi] = floatx4{bv[bi], bv[bi], bv[bi], bv[bi]};
        #pragma unroll
        for (int s = 0; s < NS; ++s) {
            const short8 af = *(const short8*)(xr + s * 32);
            #pragma unroll
            for (int bi = 0; bi < 4; ++bi)
                acc[bi] = __builtin_amdgcn_mfma_f32_16x16x32_bf16(af, bf[s][bi], acc[bi], 0, 0, 0);
        }
        #pragma unroll
        for (int r = 0; r < 4; ++r) {
            const int mi = q * 4 + r;
            if (mi < L) {
                const int tr = perm[boff + o + mi];      // LDS broadcast
                float* orow = out + (size_t)(t0 + tr) * NOUT + n_base + m;
                #pragma unroll
                for (int bi = 0; bi < 4; ++bi) orow[bi * 16] = acc[bi][r];
            }
        }
    }
}

// 64 consecutive tokens per block (contiguous x read), block-local counting sort
// into per-expert groups in LDS, x staged fp32->bf16 once, direct out writes.
__global__ __launch_bounds__(512) void misl_main(
    const float* __restrict__ x, const int* __restrict__ feat,
    const ushort* __restrict__ wb, const float* __restrict__ b,
    float* __restrict__ out, int n) {
    __shared__ ushort xs[TPB * PITCH];
    __shared__ int perm[TPB];
    __shared__ int cnt[NEXP];
    __shared__ int base[NEXP];

    const int tid = threadIdx.x;
    const int t0 = blockIdx.x * TPB;
    const int nt = (n - t0 < TPB) ? (n - t0) : TPB;

    if (tid < NEXP) cnt[tid] = 0;

    // stage x: 8 threads per row, 16 consecutive floats each (32 KB contiguous)
    const int row = tid >> 3;
    const int colu = (tid & 7) * 16;
    float4 a0, a1, a2, a3;
    const bool stg = (row < nt);
    if (stg) {
        const float* xp = x + (size_t)(t0 + row) * MAXF + colu;
        a0 = *(const float4*)xp;
        a1 = *(const float4*)(xp + 4);
        a2 = *(const float4*)(xp + 8);
        a3 = *(const float4*)(xp + 12);
    }
    __syncthreads();                               // cnt zeroed

    int e = 0, r = 0;
    if (tid < nt) {
        e = __ffs((uint)feat[t0 + tid]) - 4;       // 8->0,16->1,32->2,64->3,128->4
        r = atomicAdd(&cnt[e], 1);
    }
    if (stg) {
        short8 v0, v1;
        v0[0] = (short)f2bf(a0.x); v0[1] = (short)f2bf(a0.y);
        v0[2] = (short)f2bf(a0.z); v0[3] = (short)f2bf(a0.w);
        v0[4] = (short)f2bf(a1.x); v0[5] = (short)f2bf(a1.y);
        v0[6] = (short)f2bf(a1.z); v0[7] = (short)f2bf(a1.w);
        v1[0] = (short)f2bf(a2.x); v1[1] = (short)f2bf(a2.y);
        v1[2] = (short)f2bf(a2.z); v1[3] = (short)f2bf(a2.w);
        v1[4] = (short)f2bf(a3.x); v1[5] = (short)f2bf(a3.y);
        v1[6] = (short)f2bf(a3.z); v1[7] = (short)f2bf(a3.w);
        *(short8*)(xs + (size_t)row * PITCH + colu)     = v0;
        *(short8*)(xs + (size_t)row * PITCH + colu + 8) = v1;
    }
    __syncthreads();                               // cnt final
    if (tid == 0) {                                // heavy experts first
        int o = 0;
        #pragma unroll
        for (int j = NEXP - 1; j >= 0; --j) { base[j] = o; o += cnt[j]; }
    }
    __syncthreads();                               // base ready
    if (tid < nt) perm[base[e] + r] = tid;
    __syncthreads();                               // perm + xs ready

    const int lane = tid & 63;
    const int n_base = (tid >> 6) * 64;            // wave -> 64-col slice
    const int c0 = cnt[0], c1 = cnt[1], c2 = cnt[2], c3 = cnt[3], c4 = cnt[4];
    const int b0 = base[0], b1 = base[1], b2 = base[2], b3 = base[3], b4 = base[4];

    if (c4) run_expert<4>(xs, perm, wb, b, out, t0, b4, c4, lane, n_base);
    if (c3) run_expert<3>(xs, perm, wb, b, out, t0, b3, c3, lane, n_base);
    if (c2) run_expert<2>(xs, perm, wb, b, out, t0, b2, c2, lane, n_base);
    if (c1) run_expert<1>(xs, perm, wb, b, out, t0, b1, c1, lane, n_base);
    if (c0) run_expert<0>(xs, perm, wb, b, out, t0, b0, c0, lane, n_base);
}

extern "C" void kernel_launch(void* const* d_in, const int* in_sizes, int n_in,
                              void* d_out, int out_size, void* d_ws, size_t ws_size,
                              hipStream_t stream) {
    const float* x    = (const float*)d_in[0];
    const int*   feat = (const int*)d_in[1];
    const float* w    = (const float*)d_in[2];
    const float* b    = (const float*)d_in[3];
    float* out = (float*)d_out;
    ushort* wb = (ushort*)d_ws;                    // 655 KB bf16 B-frag pack

    const int n = in_sizes[1];                     // tokens = 32768
    misl_pack<<<160, 256, 0, stream>>>(w, wb);
    misl_main<<<(n + TPB - 1) / TPB, 512, 0, stream>>>(x, feat, wb, b, out, n);
}